// Round 3
// baseline (56.414 us; speedup 1.0000x reference)
//
#include <hip/hip_runtime.h>

#define N_NODES   200000
#define N_PATCHES 256
#define TSTEPS    12
#define NHID      16
#define HORIZON   12
#define GDIM      192            // NHID * TSTEPS
#define IN_DIM    204            // GDIM + TSTEPS

// ---------------------------------------------------------------------------
// Kernel 1: per-patch layer-1 partial (EXACT round-1 version — proven
// replay-deterministic):
//   patch_h[p][j] = b1[j] + sum_{i<192} patch_feat[p][i] * W1[i][j]
// Also builds wcomb[j][0..23] = { W1[192+t][j] (t=0..11), W2[j][o] (o=0..11) }.
// ---------------------------------------------------------------------------
__global__ __launch_bounds__(256) void patch_precompute(
    const float* __restrict__ mixer_x,   // (1,12,256,16)
    const float* __restrict__ W1,        // (204,204)
    const float* __restrict__ b1,        // (204)
    const float* __restrict__ W2,        // (204,12)
    float* __restrict__ patch_h,         // (256,204)
    float* __restrict__ wcomb)           // (204,24)
{
    __shared__ float xs[GDIM];
    const int p   = blockIdx.x;
    const int tid = threadIdx.x;

    if (tid < GDIM) {
        const int t = tid >> 4, f = tid & 15;
        xs[tid] = mixer_x[(t * N_PATCHES + p) * NHID + f];
    }
    __syncthreads();

    if (tid < IN_DIM) {
        float acc = b1[tid];
#pragma unroll 8
        for (int i = 0; i < GDIM; ++i)
            acc = fmaf(xs[i], W1[i * IN_DIM + tid], acc);
        patch_h[p * IN_DIM + tid] = acc;
    }

    if (p == 0) {
        for (int idx = tid; idx < IN_DIM * 24; idx += 256) {
            const int j = idx / 24;
            const int c = idx - j * 24;
            float v;
            if (c < 12) v = W1[(GDIM + c) * IN_DIM + j];
            else        v = W2[j * HORIZON + (c - 12)];
            wcomb[idx] = v;
        }
    }
}

// ---------------------------------------------------------------------------
// Kernel 2: per-node fused MLP. Round-1 body (proven deterministic, low
// VGPR), with the single change: 1 node/thread instead of 2 -> 2x the waves
// (3128 total, ~3/SIMD) so TLP hides the per-iteration scalar-load waits.
// ---------------------------------------------------------------------------
__global__ __launch_bounds__(256) void node_mlp(
    const float* __restrict__ features,   // (200000,12)
    const int*   __restrict__ node_patch, // (200000)
    const float* __restrict__ patch_h,    // (256,204)
    const float* __restrict__ wcomb,      // (204,24) viewed as (51,96)
    const float* __restrict__ b2,         // (12)
    float* __restrict__ out)              // (200000,12)
{
    const int n = blockIdx.x * 256 + threadIdx.x;
    if (n >= N_NODES) return;   // 200000 = 3125 full waves: whole-wave exits

    // node features (12) via 3x float4
    float f0[12];
    {
        const float4* fp0 = (const float4*)(features + n * 12);
#pragma unroll
        for (int q = 0; q < 3; ++q) {
            float4 a = fp0[q];
            f0[4*q+0] = a.x; f0[4*q+1] = a.y; f0[4*q+2] = a.z; f0[4*q+3] = a.w;
        }
    }

    const int p0 = node_patch[n];
    const float4* ph0 = (const float4*)(patch_h + p0 * IN_DIM);

    float o0[12];
#pragma unroll
    for (int t = 0; t < 12; ++t) o0[t] = b2[t];

    float4 a0 = ph0[0];

    for (int jb = 0; jb < 51; ++jb) {
        const float4 c0 = a0;
        if (jb < 50) a0 = ph0[jb + 1];       // prefetch next chunk
        const float cc0[4] = {c0.x, c0.y, c0.z, c0.w};
        const float* w = wcomb + jb * 96;
#pragma unroll
        for (int q = 0; q < 4; ++q) {
            const float* wq = w + q * 24;
            float h0 = cc0[q];
#pragma unroll
            for (int t = 0; t < 12; ++t) {
                const float wv = wq[t];
                h0 = fmaf(f0[t], wv, h0);
            }
            h0 = fmaxf(h0, 0.0f);
#pragma unroll
            for (int t = 0; t < 12; ++t) {
                const float wv = wq[12 + t];
                o0[t] = fmaf(h0, wv, o0[t]);
            }
        }
    }

    float4* op = (float4*)(out + n * 12);
    op[0] = make_float4(o0[0], o0[1], o0[2],  o0[3]);
    op[1] = make_float4(o0[4], o0[5], o0[6],  o0[7]);
    op[2] = make_float4(o0[8], o0[9], o0[10], o0[11]);
}

// ---------------------------------------------------------------------------
extern "C" void kernel_launch(void* const* d_in, const int* in_sizes, int n_in,
                              void* d_out, int out_size, void* d_ws, size_t ws_size,
                              hipStream_t stream) {
    const float* mixer_x    = (const float*)d_in[0];
    const float* features   = (const float*)d_in[1];
    const float* W1         = (const float*)d_in[2];
    const float* b1         = (const float*)d_in[3];
    const float* W2         = (const float*)d_in[4];
    const float* b2         = (const float*)d_in[5];
    const int*   node_patch = (const int*)d_in[6];
    float* out = (float*)d_out;

    float* patch_h = (float*)d_ws;                     // 256*204*4 = 208896 B
    float* wcomb   = patch_h + N_PATCHES * IN_DIM;     // +204*24*4 = 19584 B

    patch_precompute<<<N_PATCHES, 256, 0, stream>>>(mixer_x, W1, b1, W2,
                                                    patch_h, wcomb);

    const int nblocks = (N_NODES + 255) / 256;         // 782
    node_mlp<<<nblocks, 256, 0, stream>>>(features, node_patch, patch_h,
                                          wcomb, b2, out);
}

// Round 5
// 44.388 us; speedup vs baseline: 1.2709x; 1.2709x over previous
//
#include <hip/hip_runtime.h>
#include <hip/hip_bf16.h>

#define N_NODES   200000
#define N_PATCHES 256
#define TSTEPS    12
#define NHID      16
#define HORIZON   12
#define GDIM      192            // NHID * TSTEPS
#define IN_DIM    204            // GDIM + TSTEPS

typedef __attribute__((ext_vector_type(8)))  short bf16x8;
typedef __attribute__((ext_vector_type(16))) float f32x16;

union FragU { unsigned int u[4]; bf16x8 v; };

// pack two fp32 -> one dword of 2 bf16 (RNE)
__device__ __forceinline__ unsigned int pk2(float lo, float hi) {
    unsigned short l = __builtin_bit_cast(unsigned short, __float2bfloat16(lo));
    unsigned short h = __builtin_bit_cast(unsigned short, __float2bfloat16(hi));
    return ((unsigned int)h << 16) | (unsigned int)l;
}

// ---------------------------------------------------------------------------
// Kernel 1: per-patch layer-1 partial (proven replay-deterministic):
//   patch_h[p][j] = b1[j] + sum_{i<192} patch_feat[p][i] * W1[i][j]
// ---------------------------------------------------------------------------
__global__ __launch_bounds__(256) void patch_precompute(
    const float* __restrict__ mixer_x,   // (1,12,256,16)
    const float* __restrict__ W1,        // (204,204)
    const float* __restrict__ b1,        // (204)
    float* __restrict__ patch_h)         // (256,204)
{
    __shared__ float xs[GDIM];
    const int p   = blockIdx.x;
    const int tid = threadIdx.x;

    if (tid < GDIM) {
        const int t = tid >> 4, f = tid & 15;
        xs[tid] = mixer_x[(t * N_PATCHES + p) * NHID + f];
    }
    __syncthreads();

    if (tid < IN_DIM) {
        float acc = b1[tid];
#pragma unroll 8
        for (int i = 0; i < GDIM; ++i)
            acc = fmaf(xs[i], W1[i * IN_DIM + tid], acc);
        patch_h[p * IN_DIM + tid] = acc;
    }
}

// ---------------------------------------------------------------------------
// Clamped weight fetch helpers (OOB -> 0)
// ---------------------------------------------------------------------------
__device__ __forceinline__ float ldW1f(const float* __restrict__ W1, int k, int j) {
    // W1f^T[j][k] = W1[192+k][j], valid for k<12, j<204
    const bool ok = (k < TSTEPS) && (j < IN_DIM);
    const int  idx = ok ? ((GDIM + k) * IN_DIM + j) : 0;
    const float v = W1[idx];
    return ok ? v : 0.0f;
}

__device__ __forceinline__ float ldW2t(const float* __restrict__ W2, int j, int o) {
    // W2^T[o][j] = W2[j][o], valid for j<204, o<12
    const bool ok = (j < IN_DIM) && (o < HORIZON);
    const int  idx = ok ? (j * HORIZON + o) : 0;
    const float v = W2[idx];
    return ok ? v : 0.0f;
}

// ---------------------------------------------------------------------------
// Kernel 2: per-wave MFMA fused MLP. Each wave owns 64 nodes (2 chunks of 32).
// GEMM1 (swapped): h^T[j][n] = W1f^T(32x16) x F^T(16x32), C-init = PH fp32
// GEMM2 (swapped): out^T[o][n] = sum_kt W2^T(32x16) x h^T-tile
//
// Fragment packing uses the STACKED k-layout m(e,hi) = (e&3)+8*(e>>2)+4*hi
// on BOTH A and B of each GEMM. The verified 32x32 C/D row formula equals
// m(e,hi), so GEMM1's accumulator packs DIRECTLY into GEMM2's B operand —
// no cross-lane ops anywhere. Matched conventions on A/B make the result
// correct under either k-layout hypothesis (shared bijection cancels).
// ---------------------------------------------------------------------------
__global__ __launch_bounds__(256) void node_mlp_mfma(
    const float* __restrict__ features,   // (200000,12)
    const int*   __restrict__ node_patch, // (200000)
    const float* __restrict__ patch_h,    // (256,204)
    const float* __restrict__ W1,         // (204,204)
    const float* __restrict__ W2,         // (204,12)
    const float* __restrict__ b2,         // (12)
    float* __restrict__ out)              // (200000,12)
{
    const int lane = threadIdx.x & 63;
    const int wid  = threadIdx.x >> 6;
    const int jl   = lane & 31;       // row (A) / node-col (B,C,D) within tile
    const int hi   = lane >> 5;
    const int kb   = 4 * hi;          // stacked-layout k base

    // ---- one-time per-wave weight fragments -------------------------------
    bf16x8 A1f[7];                    // W1f^T tiles: row j = t*32+jl
#pragma unroll
    for (int t = 0; t < 7; ++t) {
        const int j = t * 32 + jl;
        FragU u;
        u.u[0] = pk2(ldW1f(W1, kb + 0,  j), ldW1f(W1, kb + 1,  j));
        u.u[1] = pk2(ldW1f(W1, kb + 2,  j), ldW1f(W1, kb + 3,  j));
        u.u[2] = pk2(ldW1f(W1, kb + 8,  j), ldW1f(W1, kb + 9,  j));
        u.u[3] = pk2(ldW1f(W1, kb + 10, j), ldW1f(W1, kb + 11, j));
        A1f[t] = u.v;
    }

    bf16x8 A2f[13];                   // W2^T tiles: row o = jl, k-dim = j
#pragma unroll
    for (int kt = 0; kt < 13; ++kt) {
        const int j0 = kt * 16 + kb;
        FragU u;
        u.u[0] = pk2(ldW2t(W2, j0 + 0,  jl), ldW2t(W2, j0 + 1,  jl));
        u.u[1] = pk2(ldW2t(W2, j0 + 2,  jl), ldW2t(W2, j0 + 3,  jl));
        u.u[2] = pk2(ldW2t(W2, j0 + 8,  jl), ldW2t(W2, j0 + 9,  jl));
        u.u[3] = pk2(ldW2t(W2, j0 + 10, jl), ldW2t(W2, j0 + 11, jl));
        A2f[kt] = u.v;
    }

    const float4 b2A = *(const float4*)(b2 + 4 * hi);  // hi0: b2[0..3], hi1: b2[4..7]
    const float4 b2B = *(const float4*)(b2 + 8);       // b2[8..11] (hi0 only)

    // ---- 2 chunks of 32 nodes each ----------------------------------------
#pragma unroll
    for (int chunk = 0; chunk < 2; ++chunk) {
        const int node   = blockIdx.x * 256 + wid * 64 + chunk * 32 + jl;
        const int nclamp = (node < N_NODES) ? node : (N_NODES - 1);

        // B1 operand: F^T[k][node], stacked layout:
        //   e0..3 -> k = 4hi..4hi+3 ; e4..7 -> k = 8+4hi..11+4hi (k>=12 -> 0)
        const float4* fp = (const float4*)(features + nclamp * TSTEPS);
        const float4 fa = fp[0], fb = fp[1], fc = fp[2];
        FragU b1u;
        b1u.u[0] = hi ? pk2(fb.x, fb.y) : pk2(fa.x, fa.y);
        b1u.u[1] = hi ? pk2(fb.z, fb.w) : pk2(fa.z, fa.w);
        b1u.u[2] = hi ? 0u              : pk2(fc.x, fc.y);
        b1u.u[3] = hi ? 0u              : pk2(fc.z, fc.w);
        const bf16x8 B1 = b1u.v;

        const int p = node_patch[nclamp];
        const float* phrow = patch_h + p * IN_DIM;

        f32x16 oacc;
#pragma unroll
        for (int e = 0; e < 16; ++e) oacc[e] = 0.0f;

#pragma unroll
        for (int t = 0; t < 7; ++t) {
            // C-init: PH^T[j][node] fp32; C row of elem e = (e&3)+8(e>>2)+4hi
            f32x16 acc;
#pragma unroll
            for (int G = 0; G < 4; ++G) {
                const int off = t * 32 + 8 * G + 4 * hi;
                const bool ok = (off <= 200);               // off+3 <= 203
                const float4* ap = (const float4*)(phrow + (ok ? off : 0));
                const float4 c4 = *ap;
                acc[4 * G + 0] = ok ? c4.x : 0.0f;
                acc[4 * G + 1] = ok ? c4.y : 0.0f;
                acc[4 * G + 2] = ok ? c4.z : 0.0f;
                acc[4 * G + 3] = ok ? c4.w : 0.0f;
            }

            acc = __builtin_amdgcn_mfma_f32_32x32x16_bf16(A1f[t], B1, acc, 0, 0, 0);

            // relu + pack: acc element order IS the B-operand element order
            FragU ba;
            ba.u[0] = pk2(fmaxf(acc[0],  0.f), fmaxf(acc[1],  0.f));
            ba.u[1] = pk2(fmaxf(acc[2],  0.f), fmaxf(acc[3],  0.f));
            ba.u[2] = pk2(fmaxf(acc[4],  0.f), fmaxf(acc[5],  0.f));
            ba.u[3] = pk2(fmaxf(acc[6],  0.f), fmaxf(acc[7],  0.f));
            oacc = __builtin_amdgcn_mfma_f32_32x32x16_bf16(A2f[2 * t], ba.v, oacc, 0, 0, 0);

            if (t < 6) {
                FragU bb;
                bb.u[0] = pk2(fmaxf(acc[8],  0.f), fmaxf(acc[9],  0.f));
                bb.u[1] = pk2(fmaxf(acc[10], 0.f), fmaxf(acc[11], 0.f));
                bb.u[2] = pk2(fmaxf(acc[12], 0.f), fmaxf(acc[13], 0.f));
                bb.u[3] = pk2(fmaxf(acc[14], 0.f), fmaxf(acc[15], 0.f));
                oacc = __builtin_amdgcn_mfma_f32_32x32x16_bf16(A2f[2 * t + 1], bb.v, oacc, 0, 0, 0);
            }
        }

        // ---- store: D row of elem e = (e&3)+8*(e>>2)+4*hi, col = node -----
        if (node < N_NODES) {
            float* orow = out + node * HORIZON;
            if (hi == 0) {
                float4 s0 = make_float4(oacc[0] + b2A.x, oacc[1] + b2A.y,
                                        oacc[2] + b2A.z, oacc[3] + b2A.w);
                float4 s1 = make_float4(oacc[4] + b2B.x, oacc[5] + b2B.y,
                                        oacc[6] + b2B.z, oacc[7] + b2B.w);
                *(float4*)(orow + 0) = s0;   // o = 0..3
                *(float4*)(orow + 8) = s1;   // o = 8..11
            } else {
                float4 s0 = make_float4(oacc[0] + b2A.x, oacc[1] + b2A.y,
                                        oacc[2] + b2A.z, oacc[3] + b2A.w);
                *(float4*)(orow + 4) = s0;   // o = 4..7
            }
        }
    }
}

// ---------------------------------------------------------------------------
extern "C" void kernel_launch(void* const* d_in, const int* in_sizes, int n_in,
                              void* d_out, int out_size, void* d_ws, size_t ws_size,
                              hipStream_t stream) {
    const float* mixer_x    = (const float*)d_in[0];
    const float* features   = (const float*)d_in[1];
    const float* W1         = (const float*)d_in[2];
    const float* b1         = (const float*)d_in[3];
    const float* W2         = (const float*)d_in[4];
    const float* b2         = (const float*)d_in[5];
    const int*   node_patch = (const int*)d_in[6];
    float* out = (float*)d_out;

    float* patch_h = (float*)d_ws;                     // 256*204*4 = 208896 B

    patch_precompute<<<N_PATCHES, 256, 0, stream>>>(mixer_x, W1, b1, patch_h);

    // 782 blocks x 4 waves x 64 nodes = 200192 >= 200000
    node_mlp_mfma<<<782, 256, 0, stream>>>(features, node_patch, patch_h,
                                           W1, W2, b2, out);
}

// Round 6
// 44.149 us; speedup vs baseline: 1.2778x; 1.0054x over previous
//
#include <hip/hip_runtime.h>
#include <hip/hip_bf16.h>

#define N_NODES   200000
#define N_PATCHES 256
#define TSTEPS    12
#define NHID      16
#define HORIZON   12
#define GDIM      192            // NHID * TSTEPS
#define IN_DIM    204            // GDIM + TSTEPS

typedef __attribute__((ext_vector_type(8)))  short        bf16x8;
typedef __attribute__((ext_vector_type(16))) float        f32x16;
typedef __attribute__((ext_vector_type(4)))  unsigned int u32x4;

// pack two fp32 -> one dword of 2 bf16 (RNE) — value ops only
__device__ __forceinline__ unsigned int pk2(float lo, float hi) {
    unsigned short l = __builtin_bit_cast(unsigned short, __float2bfloat16(lo));
    unsigned short h = __builtin_bit_cast(unsigned short, __float2bfloat16(hi));
    return ((unsigned int)h << 16) | (unsigned int)l;
}

__device__ __forceinline__ bf16x8 frag_of(unsigned int a, unsigned int b,
                                          unsigned int c, unsigned int d) {
    u32x4 u; u[0] = a; u[1] = b; u[2] = c; u[3] = d;
    return __builtin_bit_cast(bf16x8, u);
}

// ---------------------------------------------------------------------------
// Kernel 1: per-patch layer-1 partial (proven replay-deterministic):
//   patch_h[p][j] = b1[j] + sum_{i<192} patch_feat[p][i] * W1[i][j]
// ---------------------------------------------------------------------------
__global__ __launch_bounds__(256) void patch_precompute(
    const float* __restrict__ mixer_x,   // (1,12,256,16)
    const float* __restrict__ W1,        // (204,204)
    const float* __restrict__ b1,        // (204)
    float* __restrict__ patch_h)         // (256,204)
{
    __shared__ float xs[GDIM];
    const int p   = blockIdx.x;
    const int tid = threadIdx.x;

    if (tid < GDIM) {
        const int t = tid >> 4, f = tid & 15;
        xs[tid] = mixer_x[(t * N_PATCHES + p) * NHID + f];
    }
    __syncthreads();

    if (tid < IN_DIM) {
        float acc = b1[tid];
#pragma unroll 8
        for (int i = 0; i < GDIM; ++i)
            acc = fmaf(xs[i], W1[i * IN_DIM + tid], acc);
        patch_h[p * IN_DIM + tid] = acc;
    }
}

// ---------------------------------------------------------------------------
// Clamped weight fetch helpers (OOB -> 0)
// ---------------------------------------------------------------------------
__device__ __forceinline__ float ldW1f(const float* __restrict__ W1, int k, int j) {
    const bool ok = (k < TSTEPS) && (j < IN_DIM);
    const int  idx = ok ? ((GDIM + k) * IN_DIM + j) : 0;
    const float v = W1[idx];
    return ok ? v : 0.0f;
}

__device__ __forceinline__ float ldW2t(const float* __restrict__ W2, int j, int o) {
    const bool ok = (j < IN_DIM) && (o < HORIZON);
    const int  idx = ok ? (j * HORIZON + o) : 0;
    const float v = W2[idx];
    return ok ? v : 0.0f;
}

// clamped+zeroed C-init gather (identical semantics to R5)
__device__ __forceinline__ float4 ld_ph(const float* __restrict__ phrow, int off) {
    const bool ok = (off <= 200);                 // off+3 <= 203
    const float4 v = *(const float4*)(phrow + (ok ? off : 0));
    return make_float4(ok ? v.x : 0.0f, ok ? v.y : 0.0f,
                       ok ? v.z : 0.0f, ok ? v.w : 0.0f);
}

// ---------------------------------------------------------------------------
// Kernel 2: per-wave MFMA fused MLP. Each wave owns 64 nodes (2 chunks of 32).
// GEMM1 (swapped): h^T[j][n] = W1f^T(32x16) x F^T(16x32), C-init = PH fp32
// GEMM2 (swapped): out^T[o][n] = sum_kt W2^T(32x16) x h^T-tile
// Stacked k-layout m(e,hi) = (e&3)+8*(e>>2)+4*hi on all A/B fragments; the
// verified 32x32 C/D row formula equals m(e,hi), so GEMM1's accumulator packs
// directly into GEMM2's B operand. No unions (bit_cast value ops only);
// C-init gathers are software-pipelined one tile ahead.
// ---------------------------------------------------------------------------
__global__ __launch_bounds__(256) void node_mlp_mfma(
    const float* __restrict__ features,   // (200000,12)
    const int*   __restrict__ node_patch, // (200000)
    const float* __restrict__ patch_h,    // (256,204)
    const float* __restrict__ W1,         // (204,204)
    const float* __restrict__ W2,         // (204,12)
    const float* __restrict__ b2,         // (12)
    float* __restrict__ out)              // (200000,12)
{
    const int lane = threadIdx.x & 63;
    const int wid  = threadIdx.x >> 6;
    const int jl   = lane & 31;
    const int hi   = lane >> 5;
    const int kb   = 4 * hi;          // stacked-layout k base

    // ---- one-time per-wave weight fragments -------------------------------
    bf16x8 A1f[7];                    // W1f^T tiles: row j = t*32+jl
#pragma unroll
    for (int t = 0; t < 7; ++t) {
        const int j = t * 32 + jl;
        A1f[t] = frag_of(pk2(ldW1f(W1, kb + 0,  j), ldW1f(W1, kb + 1,  j)),
                         pk2(ldW1f(W1, kb + 2,  j), ldW1f(W1, kb + 3,  j)),
                         pk2(ldW1f(W1, kb + 8,  j), ldW1f(W1, kb + 9,  j)),
                         pk2(ldW1f(W1, kb + 10, j), ldW1f(W1, kb + 11, j)));
    }

    bf16x8 A2f[13];                   // W2^T tiles: row o = jl, k-dim = j
#pragma unroll
    for (int kt = 0; kt < 13; ++kt) {
        const int j0 = kt * 16 + kb;
        A2f[kt] = frag_of(pk2(ldW2t(W2, j0 + 0,  jl), ldW2t(W2, j0 + 1,  jl)),
                          pk2(ldW2t(W2, j0 + 2,  jl), ldW2t(W2, j0 + 3,  jl)),
                          pk2(ldW2t(W2, j0 + 8,  jl), ldW2t(W2, j0 + 9,  jl)),
                          pk2(ldW2t(W2, j0 + 10, jl), ldW2t(W2, j0 + 11, jl)));
    }

    const float4 b2A = *(const float4*)(b2 + 4 * hi);  // hi0: b2[0..3], hi1: b2[4..7]
    const float4 b2B = *(const float4*)(b2 + 8);       // b2[8..11] (hi0 only)

    // ---- 2 chunks of 32 nodes each ----------------------------------------
#pragma unroll
    for (int chunk = 0; chunk < 2; ++chunk) {
        const int node   = blockIdx.x * 256 + wid * 64 + chunk * 32 + jl;
        const int nclamp = (node < N_NODES) ? node : (N_NODES - 1);

        // B1 operand: F^T[k][node], stacked layout (k>=12 -> 0)
        const float4* fp = (const float4*)(features + nclamp * TSTEPS);
        const float4 fa = fp[0], fb = fp[1], fc = fp[2];
        const bf16x8 B1 = frag_of(hi ? pk2(fb.x, fb.y) : pk2(fa.x, fa.y),
                                  hi ? pk2(fb.z, fb.w) : pk2(fa.z, fa.w),
                                  hi ? 0u              : pk2(fc.x, fc.y),
                                  hi ? 0u              : pk2(fc.z, fc.w));

        const int p = node_patch[nclamp];
        const float* phrow = patch_h + p * IN_DIM;

        f32x16 oacc;
#pragma unroll
        for (int e = 0; e < 16; ++e) oacc[e] = 0.0f;

        // prefetch tile 0's C-init
        float4 c0 = ld_ph(phrow, 0  + kb);
        float4 c1 = ld_ph(phrow, 8  + kb);
        float4 c2 = ld_ph(phrow, 16 + kb);
        float4 c3 = ld_ph(phrow, 24 + kb);

#pragma unroll
        for (int t = 0; t < 7; ++t) {
            f32x16 acc;
            acc[0]  = c0.x; acc[1]  = c0.y; acc[2]  = c0.z; acc[3]  = c0.w;
            acc[4]  = c1.x; acc[5]  = c1.y; acc[6]  = c1.z; acc[7]  = c1.w;
            acc[8]  = c2.x; acc[9]  = c2.y; acc[10] = c2.z; acc[11] = c2.w;
            acc[12] = c3.x; acc[13] = c3.y; acc[14] = c3.z; acc[15] = c3.w;

            if (t < 6) {               // issue next tile's gathers early
                const int base = (t + 1) * 32 + kb;
                c0 = ld_ph(phrow, base + 0);
                c1 = ld_ph(phrow, base + 8);
                c2 = ld_ph(phrow, base + 16);
                c3 = ld_ph(phrow, base + 24);
            }

            acc = __builtin_amdgcn_mfma_f32_32x32x16_bf16(A1f[t], B1, acc, 0, 0, 0);

            // relu + pack: acc element order IS the B-operand element order
            const bf16x8 ba = frag_of(
                pk2(fmaxf(acc[0], 0.f), fmaxf(acc[1], 0.f)),
                pk2(fmaxf(acc[2], 0.f), fmaxf(acc[3], 0.f)),
                pk2(fmaxf(acc[4], 0.f), fmaxf(acc[5], 0.f)),
                pk2(fmaxf(acc[6], 0.f), fmaxf(acc[7], 0.f)));
            oacc = __builtin_amdgcn_mfma_f32_32x32x16_bf16(A2f[2 * t], ba, oacc, 0, 0, 0);

            if (t < 6) {
                const bf16x8 bb = frag_of(
                    pk2(fmaxf(acc[8],  0.f), fmaxf(acc[9],  0.f)),
                    pk2(fmaxf(acc[10], 0.f), fmaxf(acc[11], 0.f)),
                    pk2(fmaxf(acc[12], 0.f), fmaxf(acc[13], 0.f)),
                    pk2(fmaxf(acc[14], 0.f), fmaxf(acc[15], 0.f)));
                oacc = __builtin_amdgcn_mfma_f32_32x32x16_bf16(A2f[2 * t + 1], bb, oacc, 0, 0, 0);
            }
        }

        // ---- store: D row of elem e = (e&3)+8*(e>>2)+4*hi, col = node -----
        if (node < N_NODES) {
            float* orow = out + node * HORIZON;
            if (hi == 0) {
                float4 s0 = make_float4(oacc[0] + b2A.x, oacc[1] + b2A.y,
                                        oacc[2] + b2A.z, oacc[3] + b2A.w);
                float4 s1 = make_float4(oacc[4] + b2B.x, oacc[5] + b2B.y,
                                        oacc[6] + b2B.z, oacc[7] + b2B.w);
                *(float4*)(orow + 0) = s0;   // o = 0..3
                *(float4*)(orow + 8) = s1;   // o = 8..11
            } else {
                float4 s0 = make_float4(oacc[0] + b2A.x, oacc[1] + b2A.y,
                                        oacc[2] + b2A.z, oacc[3] + b2A.w);
                *(float4*)(orow + 4) = s0;   // o = 4..7
            }
        }
    }
}

// ---------------------------------------------------------------------------
extern "C" void kernel_launch(void* const* d_in, const int* in_sizes, int n_in,
                              void* d_out, int out_size, void* d_ws, size_t ws_size,
                              hipStream_t stream) {
    const float* mixer_x    = (const float*)d_in[0];
    const float* features   = (const float*)d_in[1];
    const float* W1         = (const float*)d_in[2];
    const float* b1         = (const float*)d_in[3];
    const float* W2         = (const float*)d_in[4];
    const float* b2         = (const float*)d_in[5];
    const int*   node_patch = (const int*)d_in[6];
    float* out = (float*)d_out;

    float* patch_h = (float*)d_ws;                     // 256*204*4 = 208896 B

    patch_precompute<<<N_PATCHES, 256, 0, stream>>>(mixer_x, W1, b1, patch_h);

    // 782 blocks x 4 waves x 64 nodes = 200192 >= 200000
    node_mlp_mfma<<<782, 256, 0, stream>>>(features, node_patch, patch_h,
                                           W1, W2, b2, out);
}

// Round 7
// 38.009 us; speedup vs baseline: 1.4842x; 1.1615x over previous
//
#include <hip/hip_runtime.h>
#include <hip/hip_bf16.h>

#define N_NODES   200000
#define N_PATCHES 256
#define TSTEPS    12
#define NHID      16
#define HORIZON   12
#define GDIM      192            // NHID * TSTEPS
#define IN_DIM    204            // GDIM + TSTEPS

#define NODES_PER_BLOCK 800      // 25 chunks of 32; 250 active blocks cover 200000
#define CHUNKS_PER_BLOCK 25

typedef __attribute__((ext_vector_type(8)))  short        bf16x8;
typedef __attribute__((ext_vector_type(16))) float        f32x16;
typedef __attribute__((ext_vector_type(4)))  unsigned int u32x4;

__device__ __forceinline__ unsigned int pk2(float lo, float hi) {
    unsigned short l = __builtin_bit_cast(unsigned short, __float2bfloat16(lo));
    unsigned short h = __builtin_bit_cast(unsigned short, __float2bfloat16(hi));
    return ((unsigned int)h << 16) | (unsigned int)l;
}

__device__ __forceinline__ bf16x8 frag_of(unsigned int a, unsigned int b,
                                          unsigned int c, unsigned int d) {
    u32x4 u; u[0] = a; u[1] = b; u[2] = c; u[3] = d;
    return __builtin_bit_cast(bf16x8, u);
}

__device__ __forceinline__ float bf16bits_lo(unsigned int w) {
    return __builtin_bit_cast(float, w << 16);
}
__device__ __forceinline__ float bf16bits_hi(unsigned int w) {
    return __builtin_bit_cast(float, w & 0xffff0000u);
}

// Clamped weight fetch helpers (OOB -> 0)
__device__ __forceinline__ float ldW1f(const float* __restrict__ W1, int k, int j) {
    const bool ok = (k < TSTEPS) && (j < IN_DIM);
    const int  idx = ok ? ((GDIM + k) * IN_DIM + j) : 0;
    const float v = W1[idx];
    return ok ? v : 0.0f;
}
__device__ __forceinline__ float ldW2t(const float* __restrict__ W2, int j, int o) {
    const bool ok = (j < IN_DIM) && (o < HORIZON);
    const int  idx = ok ? (j * HORIZON + o) : 0;
    const float v = W2[idx];
    return ok ? v : 0.0f;
}

// ---------------------------------------------------------------------------
// Kernel 1 (grid 257 x 512):
//  blocks 0..255 : patch_h[p][j] = b1[j] + sum_{i<192} x[p][i] * W1[i][j]
//                  (split-i across two 256-thread halves, LDS combine)
//  block 256     : pack the per-lane MFMA weight fragments into ws:
//                  wfrag[f][lane], f<7 = A1f tiles (W1 feature rows),
//                  f in 7..19 = A2f tiles (W2^T), stacked k-layout
//                  m(e,hi) = (e&3)+8*(e>>2)+4*hi.
// ---------------------------------------------------------------------------
__global__ __launch_bounds__(512) void precompute(
    const float* __restrict__ mixer_x,   // (1,12,256,16)
    const float* __restrict__ W1,        // (204,204)
    const float* __restrict__ b1,        // (204)
    const float* __restrict__ W2,        // (204,12)
    float* __restrict__ patch_h,         // (256,204)
    u32x4* __restrict__ wfrag)           // (20,64)
{
    const int blk = blockIdx.x;
    const int tid = threadIdx.x;

    if (blk == N_PATCHES) {
        const int lane = tid & 63;
        const int g    = tid >> 6;        // 0..7
        const int jl   = lane & 31;
        const int kb   = 4 * (lane >> 5);
        for (int f = g; f < 20; f += 8) {
            u32x4 u;
            if (f < 7) {
                const int j = f * 32 + jl;
                u[0] = pk2(ldW1f(W1, kb + 0,  j), ldW1f(W1, kb + 1,  j));
                u[1] = pk2(ldW1f(W1, kb + 2,  j), ldW1f(W1, kb + 3,  j));
                u[2] = pk2(ldW1f(W1, kb + 8,  j), ldW1f(W1, kb + 9,  j));
                u[3] = pk2(ldW1f(W1, kb + 10, j), ldW1f(W1, kb + 11, j));
            } else {
                const int j0 = (f - 7) * 16 + kb;
                u[0] = pk2(ldW2t(W2, j0 + 0,  jl), ldW2t(W2, j0 + 1,  jl));
                u[1] = pk2(ldW2t(W2, j0 + 2,  jl), ldW2t(W2, j0 + 3,  jl));
                u[2] = pk2(ldW2t(W2, j0 + 8,  jl), ldW2t(W2, j0 + 9,  jl));
                u[3] = pk2(ldW2t(W2, j0 + 10, jl), ldW2t(W2, j0 + 11, jl));
            }
            wfrag[f * 64 + lane] = u;
        }
        return;
    }

    __shared__ float xs[GDIM];
    __shared__ float partial[IN_DIM];
    const int p    = blk;
    const int j    = tid & 255;
    const int half = tid >> 8;

    if (tid < GDIM) {
        const int t = tid >> 4, f = tid & 15;
        xs[tid] = mixer_x[(t * N_PATCHES + p) * NHID + f];
    }
    __syncthreads();

    float acc = 0.0f;
    if (j < IN_DIM) {
        acc = half ? 0.0f : b1[j];
        const int ibase = half * 96;
#pragma unroll 8
        for (int i = 0; i < 96; ++i)
            acc = fmaf(xs[ibase + i], W1[(ibase + i) * IN_DIM + j], acc);
        if (half) partial[j] = acc;
    }
    __syncthreads();
    if (!half && j < IN_DIM)
        patch_h[p * IN_DIM + j] = acc + partial[j];
}

// ---------------------------------------------------------------------------
// Kernel 2 (grid 256 x 256, 104448 B LDS): stage FULL bf16 patch table in LDS,
// then per-wave MFMA over 800 consecutive nodes (chunks of 32).
// GEMM1 (swapped): h^T[j][n] = W1f^T x F^T + PH (C-init from LDS)
// GEMM2 (swapped): out^T[o][n] = sum_kt W2^T x h-tile; accumulator packs
// directly into GEMM2's B operand (stacked k-layout == C/D row formula).
// features / node_patch / out accesses are consecutive-node => coalesced.
// ---------------------------------------------------------------------------
__global__ __launch_bounds__(256) void node_mlp_mfma(
    const float* __restrict__ features,   // (200000,12)
    const int*   __restrict__ node_patch, // (200000)
    const float* __restrict__ patch_h,    // (256,204) fp32
    const u32x4* __restrict__ wfrag,      // (20,64)
    const float* __restrict__ b2,         // (12)
    float* __restrict__ out)              // (200000,12)
{
    __shared__ unsigned short smem[N_PATCHES * IN_DIM];   // 104448 B bf16

    const int tid  = threadIdx.x;
    const int base = blockIdx.x * NODES_PER_BLOCK;
    if (base >= N_NODES) return;          // blocks 250..255 idle (uniform exit)

    // ---- stage patch_h -> LDS bf16 (coalesced: 51 float4 per thread) ------
    {
        const float4* src = (const float4*)patch_h;       // 13056 float4
        for (int i = tid; i < (N_PATCHES * IN_DIM) / 4; i += 256) {
            const float4 v = src[i];
            ((uint2*)smem)[i] = make_uint2(pk2(v.x, v.y), pk2(v.z, v.w));
        }
    }

    // ---- per-lane weight fragments (coalesced 16B loads from ws) ----------
    const int lane = tid & 63;
    const int wid  = tid >> 6;
    const int jl   = lane & 31;
    const int hi   = lane >> 5;

    bf16x8 A1f[7], A2f[13];
#pragma unroll
    for (int f = 0; f < 7; ++f)
        A1f[f] = __builtin_bit_cast(bf16x8, wfrag[f * 64 + lane]);
#pragma unroll
    for (int f = 0; f < 13; ++f)
        A2f[f] = __builtin_bit_cast(bf16x8, wfrag[(7 + f) * 64 + lane]);

    const float4 b2A = *(const float4*)(b2 + 4 * hi);     // b2[0..3] / b2[4..7]
    const float4 b2B = *(const float4*)(b2 + 8);          // b2[8..11] (hi0)

    __syncthreads();

    // ---- chunks of 32 consecutive nodes, round-robin over 4 waves ---------
    for (int c = wid; c < CHUNKS_PER_BLOCK; c += 4) {
        const int node   = base + c * 32 + jl;
        const int nclamp = (node < N_NODES) ? node : (N_NODES - 1);

        // B1: F^T[k][node], stacked layout (k>=12 -> 0); coalesced reads
        const float4* fp = (const float4*)(features + nclamp * TSTEPS);
        const float4 fa = fp[0], fb = fp[1], fc = fp[2];
        const bf16x8 B1 = frag_of(hi ? pk2(fb.x, fb.y) : pk2(fa.x, fa.y),
                                  hi ? pk2(fb.z, fb.w) : pk2(fa.z, fa.w),
                                  hi ? 0u              : pk2(fc.x, fc.y),
                                  hi ? 0u              : pk2(fc.z, fc.w));

        const int p = node_patch[nclamp];                 // coalesced
        const unsigned short* row = smem + p * IN_DIM;    // 408 B, 8B-aligned

        f32x16 oacc;
#pragma unroll
        for (int e = 0; e < 16; ++e) oacc[e] = 0.0f;

#pragma unroll
        for (int t = 0; t < 7; ++t) {
            // C-init: PH[p][t*32 + 8G + 4hi + q] from LDS (bf16 -> fp32)
            f32x16 acc;
#pragma unroll
            for (int G = 0; G < 4; ++G) {
                const int eoff = t * 32 + 8 * G + 4 * hi;
                const bool ok  = (eoff <= 200);           // eoff+3 <= 203
                const uint2 r  = *(const uint2*)(row + (ok ? eoff : 0));
                acc[4 * G + 0] = ok ? bf16bits_lo(r.x) : 0.0f;
                acc[4 * G + 1] = ok ? bf16bits_hi(r.x) : 0.0f;
                acc[4 * G + 2] = ok ? bf16bits_lo(r.y) : 0.0f;
                acc[4 * G + 3] = ok ? bf16bits_hi(r.y) : 0.0f;
            }

            acc = __builtin_amdgcn_mfma_f32_32x32x16_bf16(A1f[t], B1, acc, 0, 0, 0);

            // relu + pack: acc element order IS the B-operand element order
            const bf16x8 ba = frag_of(
                pk2(fmaxf(acc[0], 0.f), fmaxf(acc[1], 0.f)),
                pk2(fmaxf(acc[2], 0.f), fmaxf(acc[3], 0.f)),
                pk2(fmaxf(acc[4], 0.f), fmaxf(acc[5], 0.f)),
                pk2(fmaxf(acc[6], 0.f), fmaxf(acc[7], 0.f)));
            oacc = __builtin_amdgcn_mfma_f32_32x32x16_bf16(A2f[2 * t], ba, oacc, 0, 0, 0);

            if (t < 6) {
                const bf16x8 bb = frag_of(
                    pk2(fmaxf(acc[8],  0.f), fmaxf(acc[9],  0.f)),
                    pk2(fmaxf(acc[10], 0.f), fmaxf(acc[11], 0.f)),
                    pk2(fmaxf(acc[12], 0.f), fmaxf(acc[13], 0.f)),
                    pk2(fmaxf(acc[14], 0.f), fmaxf(acc[15], 0.f)));
                oacc = __builtin_amdgcn_mfma_f32_32x32x16_bf16(A2f[2 * t + 1], bb, oacc, 0, 0, 0);
            }
        }

        // ---- store: D row of elem e = (e&3)+8*(e>>2)+4*hi, col = node -----
        if (node < N_NODES) {
            float* orow = out + node * HORIZON;
            if (hi == 0) {
                float4 s0 = make_float4(oacc[0] + b2A.x, oacc[1] + b2A.y,
                                        oacc[2] + b2A.z, oacc[3] + b2A.w);
                float4 s1 = make_float4(oacc[4] + b2B.x, oacc[5] + b2B.y,
                                        oacc[6] + b2B.z, oacc[7] + b2B.w);
                *(float4*)(orow + 0) = s0;   // o = 0..3
                *(float4*)(orow + 8) = s1;   // o = 8..11
            } else {
                float4 s0 = make_float4(oacc[0] + b2A.x, oacc[1] + b2A.y,
                                        oacc[2] + b2A.z, oacc[3] + b2A.w);
                *(float4*)(orow + 4) = s0;   // o = 4..7
            }
        }
    }
}

// ---------------------------------------------------------------------------
extern "C" void kernel_launch(void* const* d_in, const int* in_sizes, int n_in,
                              void* d_out, int out_size, void* d_ws, size_t ws_size,
                              hipStream_t stream) {
    const float* mixer_x    = (const float*)d_in[0];
    const float* features   = (const float*)d_in[1];
    const float* W1         = (const float*)d_in[2];
    const float* b1         = (const float*)d_in[3];
    const float* W2         = (const float*)d_in[4];
    const float* b2         = (const float*)d_in[5];
    const int*   node_patch = (const int*)d_in[6];
    float* out = (float*)d_out;

    float* patch_h = (float*)d_ws;                       // 208896 B
    u32x4* wfrag   = (u32x4*)((char*)d_ws + 208896);     // +20480 B

    precompute<<<257, 512, 0, stream>>>(mixer_x, W1, b1, W2, patch_h, wfrag);

    node_mlp_mfma<<<256, 256, 0, stream>>>(features, node_patch, patch_h,
                                           wfrag, b2, out);
}

// Round 8
// 28.986 us; speedup vs baseline: 1.9462x; 1.3113x over previous
//
#include <hip/hip_runtime.h>
#include <hip/hip_bf16.h>

#define N_NODES   200000
#define N_PATCHES 256
#define TSTEPS    12
#define NHID      16
#define HORIZON   12
#define GDIM      192            // NHID * TSTEPS
#define IN_DIM    204            // GDIM + TSTEPS
#define NCHUNKS   6250           // N_NODES / 32 (exact)
#define K2_THREADS 512
#define TOTAL_WAVES 2048         // 256 blocks x 8 waves

typedef __attribute__((ext_vector_type(8)))  short        bf16x8;
typedef __attribute__((ext_vector_type(16))) float        f32x16;
typedef __attribute__((ext_vector_type(4)))  unsigned int u32x4;

__device__ __forceinline__ unsigned int pk2(float lo, float hi) {
    unsigned short l = __builtin_bit_cast(unsigned short, __float2bfloat16(lo));
    unsigned short h = __builtin_bit_cast(unsigned short, __float2bfloat16(hi));
    return ((unsigned int)h << 16) | (unsigned int)l;
}

__device__ __forceinline__ bf16x8 frag_of(unsigned int a, unsigned int b,
                                          unsigned int c, unsigned int d) {
    u32x4 u; u[0] = a; u[1] = b; u[2] = c; u[3] = d;
    return __builtin_bit_cast(bf16x8, u);
}

__device__ __forceinline__ float bf16bits_lo(unsigned int w) {
    return __builtin_bit_cast(float, w << 16);
}
__device__ __forceinline__ float bf16bits_hi(unsigned int w) {
    return __builtin_bit_cast(float, w & 0xffff0000u);
}

// Clamped weight fetch helpers (OOB -> 0)
__device__ __forceinline__ float ldW1f(const float* __restrict__ W1, int k, int j) {
    const bool ok = (k < TSTEPS) && (j < IN_DIM);
    const int  idx = ok ? ((GDIM + k) * IN_DIM + j) : 0;
    const float v = W1[idx];
    return ok ? v : 0.0f;
}
__device__ __forceinline__ float ldW2t(const float* __restrict__ W2, int j, int o) {
    const bool ok = (j < IN_DIM) && (o < HORIZON);
    const int  idx = ok ? (j * HORIZON + o) : 0;
    const float v = W2[idx];
    return ok ? v : 0.0f;
}

// ---------------------------------------------------------------------------
// Kernel 1 (grid 257 x 512):
//  blocks 0..255 : patch_hb[p][j] = bf16(b1[j] + sum_{i<192} x[p][i]*W1[i][j])
//                  (split-i across two 256-thread halves, LDS combine)
//  block 256     : pack per-lane MFMA weight fragments (stacked k-layout
//                  m(e,hi) = (e&3)+8*(e>>2)+4*hi) into wfrag.
// ---------------------------------------------------------------------------
__global__ __launch_bounds__(512) void precompute(
    const float* __restrict__ mixer_x,   // (1,12,256,16)
    const float* __restrict__ W1,        // (204,204)
    const float* __restrict__ b1,        // (204)
    const float* __restrict__ W2,        // (204,12)
    unsigned short* __restrict__ patch_hb, // (256,204) bf16
    u32x4* __restrict__ wfrag)           // (20,64)
{
    const int blk = blockIdx.x;
    const int tid = threadIdx.x;

    if (blk == N_PATCHES) {
        const int lane = tid & 63;
        const int g    = tid >> 6;        // 0..7
        const int jl   = lane & 31;
        const int kb   = 4 * (lane >> 5);
        for (int f = g; f < 20; f += 8) {
            u32x4 u;
            if (f < 7) {
                const int j = f * 32 + jl;
                u[0] = pk2(ldW1f(W1, kb + 0,  j), ldW1f(W1, kb + 1,  j));
                u[1] = pk2(ldW1f(W1, kb + 2,  j), ldW1f(W1, kb + 3,  j));
                u[2] = pk2(ldW1f(W1, kb + 8,  j), ldW1f(W1, kb + 9,  j));
                u[3] = pk2(ldW1f(W1, kb + 10, j), ldW1f(W1, kb + 11, j));
            } else {
                const int j0 = (f - 7) * 16 + kb;
                u[0] = pk2(ldW2t(W2, j0 + 0,  jl), ldW2t(W2, j0 + 1,  jl));
                u[1] = pk2(ldW2t(W2, j0 + 2,  jl), ldW2t(W2, j0 + 3,  jl));
                u[2] = pk2(ldW2t(W2, j0 + 8,  jl), ldW2t(W2, j0 + 9,  jl));
                u[3] = pk2(ldW2t(W2, j0 + 10, jl), ldW2t(W2, j0 + 11, jl));
            }
            wfrag[f * 64 + lane] = u;
        }
        return;
    }

    __shared__ float xs[GDIM];
    __shared__ float partial[IN_DIM];
    const int p    = blk;
    const int j    = tid & 255;
    const int half = tid >> 8;

    if (tid < GDIM) {
        const int t = tid >> 4, f = tid & 15;
        xs[tid] = mixer_x[(t * N_PATCHES + p) * NHID + f];
    }
    __syncthreads();

    float acc = 0.0f;
    if (j < IN_DIM) {
        acc = half ? 0.0f : b1[j];
        const int ibase = half * 96;
#pragma unroll 8
        for (int i = 0; i < 96; ++i)
            acc = fmaf(xs[ibase + i], W1[(ibase + i) * IN_DIM + j], acc);
        if (half) partial[j] = acc;
    }
    __syncthreads();
    if (!half && j < IN_DIM) {
        const float v = acc + partial[j];
        patch_hb[p * IN_DIM + j] =
            __builtin_bit_cast(unsigned short, __float2bfloat16(v));
    }
}

// ---------------------------------------------------------------------------
// Kernel 2 (grid 256 x 512, 104448 B LDS, 2 waves/SIMD): stage full bf16
// patch table into LDS (raw 16B copies), then per-wave MFMA over chunks of
// 32 consecutive nodes, flat-indexed c = blk*8+wid, stride 2048 (6250 exact).
// Feature/patch loads for the NEXT chunk issue before this chunk's MFMAs.
// GEMM1 (swapped): h^T = W1f^T x F^T + PH (C-init from LDS)
// GEMM2 (swapped): out^T = sum_kt W2^T x h-tile, split into even/odd accs.
// ---------------------------------------------------------------------------
__global__ __launch_bounds__(512) void node_mlp_mfma(
    const float* __restrict__ features,       // (200000,12)
    const int*   __restrict__ node_patch,     // (200000)
    const unsigned short* __restrict__ patch_hb, // (256,204) bf16
    const u32x4* __restrict__ wfrag,          // (20,64)
    const float* __restrict__ b2,             // (12)
    float* __restrict__ out)                  // (200000,12)
{
    __shared__ unsigned short smem[N_PATCHES * IN_DIM];   // 104448 B

    const int tid = threadIdx.x;

    // ---- stage bf16 patch table -> LDS (raw copy, 6528 uint4) -------------
    {
        const uint4* src = (const uint4*)patch_hb;
        uint4* dst = (uint4*)smem;
        for (int i = tid; i < 6528; i += K2_THREADS) dst[i] = src[i];
    }

    const int lane = tid & 63;
    const int wid  = tid >> 6;
    const int jl   = lane & 31;
    const int hi   = lane >> 5;

    bf16x8 A1f[7], A2f[13];
#pragma unroll
    for (int f = 0; f < 7; ++f)
        A1f[f] = __builtin_bit_cast(bf16x8, wfrag[f * 64 + lane]);
#pragma unroll
    for (int f = 0; f < 13; ++f)
        A2f[f] = __builtin_bit_cast(bf16x8, wfrag[(7 + f) * 64 + lane]);

    const float4 b2A = *(const float4*)(b2 + 4 * hi);     // b2[0..3] / b2[4..7]
    const float4 b2B = *(const float4*)(b2 + 8);          // b2[8..11] (hi0)

    __syncthreads();

    // ---- chunk loop with depth-1 software pipeline ------------------------
    int c = blockIdx.x * 8 + wid;                         // 0..2047
    float4 fa, fb, fc; int p;
    {
        const float4* fp = (const float4*)(features + (c * 32 + jl) * TSTEPS);
        fa = fp[0]; fb = fp[1]; fc = fp[2];
        p  = node_patch[c * 32 + jl];
    }

    while (true) {
        const int  cn    = c + TOTAL_WAVES;
        const bool haveN = (cn < NCHUNKS);
        float4 fa2, fb2, fc2; int p2 = 0;
        if (haveN) {                                      // prefetch next chunk
            const float4* fq = (const float4*)(features + (cn * 32 + jl) * TSTEPS);
            fa2 = fq[0]; fb2 = fq[1]; fc2 = fq[2];
            p2  = node_patch[cn * 32 + jl];
        }

        // B1: F^T[k][node], stacked layout (k>=12 -> 0)
        const bf16x8 B1 = frag_of(hi ? pk2(fb.x, fb.y) : pk2(fa.x, fa.y),
                                  hi ? pk2(fb.z, fb.w) : pk2(fa.z, fa.w),
                                  hi ? 0u              : pk2(fc.x, fc.y),
                                  hi ? 0u              : pk2(fc.z, fc.w));

        const unsigned short* row = smem + p * IN_DIM;

        f32x16 oE, oO;
#pragma unroll
        for (int e = 0; e < 16; ++e) { oE[e] = 0.0f; oO[e] = 0.0f; }

#pragma unroll
        for (int t = 0; t < 7; ++t) {
            f32x16 acc;
#pragma unroll
            for (int G = 0; G < 4; ++G) {
                const int eoff = t * 32 + 8 * G + 4 * hi;
                const bool ok  = (eoff <= 200);           // eoff+3 <= 203
                const uint2 r  = *(const uint2*)(row + (ok ? eoff : 0));
                acc[4 * G + 0] = ok ? bf16bits_lo(r.x) : 0.0f;
                acc[4 * G + 1] = ok ? bf16bits_hi(r.x) : 0.0f;
                acc[4 * G + 2] = ok ? bf16bits_lo(r.y) : 0.0f;
                acc[4 * G + 3] = ok ? bf16bits_hi(r.y) : 0.0f;
            }

            acc = __builtin_amdgcn_mfma_f32_32x32x16_bf16(A1f[t], B1, acc, 0, 0, 0);

            const bf16x8 ba = frag_of(
                pk2(fmaxf(acc[0], 0.f), fmaxf(acc[1], 0.f)),
                pk2(fmaxf(acc[2], 0.f), fmaxf(acc[3], 0.f)),
                pk2(fmaxf(acc[4], 0.f), fmaxf(acc[5], 0.f)),
                pk2(fmaxf(acc[6], 0.f), fmaxf(acc[7], 0.f)));
            oE = __builtin_amdgcn_mfma_f32_32x32x16_bf16(A2f[2 * t], ba, oE, 0, 0, 0);

            if (t < 6) {
                const bf16x8 bb = frag_of(
                    pk2(fmaxf(acc[8],  0.f), fmaxf(acc[9],  0.f)),
                    pk2(fmaxf(acc[10], 0.f), fmaxf(acc[11], 0.f)),
                    pk2(fmaxf(acc[12], 0.f), fmaxf(acc[13], 0.f)),
                    pk2(fmaxf(acc[14], 0.f), fmaxf(acc[15], 0.f)));
                oO = __builtin_amdgcn_mfma_f32_32x32x16_bf16(A2f[2 * t + 1], bb, oO, 0, 0, 0);
            }
        }

        // ---- store: D row of elem e = (e&3)+8*(e>>2)+4*hi, col = node -----
        {
            const int node = c * 32 + jl;                 // always < N_NODES
            float* orow = out + node * HORIZON;
            const float s0 = oE[0] + oO[0], s1 = oE[1] + oO[1];
            const float s2 = oE[2] + oO[2], s3 = oE[3] + oO[3];
            if (hi == 0) {
                const float s4 = oE[4] + oO[4], s5 = oE[5] + oO[5];
                const float s6 = oE[6] + oO[6], s7 = oE[7] + oO[7];
                *(float4*)(orow + 0) = make_float4(s0 + b2A.x, s1 + b2A.y,
                                                   s2 + b2A.z, s3 + b2A.w);
                *(float4*)(orow + 8) = make_float4(s4 + b2B.x, s5 + b2B.y,
                                                   s6 + b2B.z, s7 + b2B.w);
            } else {
                *(float4*)(orow + 4) = make_float4(s0 + b2A.x, s1 + b2A.y,
                                                   s2 + b2A.z, s3 + b2A.w);
            }
        }

        if (!haveN) break;
        fa = fa2; fb = fb2; fc = fc2; p = p2; c = cn;
    }
}

// ---------------------------------------------------------------------------
extern "C" void kernel_launch(void* const* d_in, const int* in_sizes, int n_in,
                              void* d_out, int out_size, void* d_ws, size_t ws_size,
                              hipStream_t stream) {
    const float* mixer_x    = (const float*)d_in[0];
    const float* features   = (const float*)d_in[1];
    const float* W1         = (const float*)d_in[2];
    const float* b1         = (const float*)d_in[3];
    const float* W2         = (const float*)d_in[4];
    const float* b2         = (const float*)d_in[5];
    const int*   node_patch = (const int*)d_in[6];
    float* out = (float*)d_out;

    unsigned short* patch_hb = (unsigned short*)d_ws;          // 104448 B
    u32x4*          wfrag    = (u32x4*)((char*)d_ws + 104448); // +20480 B

    precompute<<<257, 512, 0, stream>>>(mixer_x, W1, b1, W2, patch_hb, wfrag);

    node_mlp_mfma<<<256, K2_THREADS, 0, stream>>>(features, node_patch,
                                                  patch_hb, wfrag, b2, out);
}

// Round 9
// 25.844 us; speedup vs baseline: 2.1829x; 1.1216x over previous
//
#include <hip/hip_runtime.h>
#include <hip/hip_bf16.h>

#define N_NODES   200000
#define N_PATCHES 256
#define TSTEPS    12
#define NHID      16
#define HORIZON   12
#define GDIM      192            // NHID * TSTEPS
#define IN_DIM    204            // GDIM + TSTEPS
#define NCHUNKS   6250           // N_NODES / 32 (exact)
#define K2_THREADS 512
#define TOTAL_WAVES 2048         // 256 blocks x 8 waves
#define TBL_U4    6528           // 256*204*2 bytes / 16

typedef __attribute__((ext_vector_type(8)))  short        bf16x8;
typedef __attribute__((ext_vector_type(16))) float        f32x16;
typedef __attribute__((ext_vector_type(4)))  unsigned int u32x4;

__device__ __forceinline__ unsigned int pk2(float lo, float hi) {
    unsigned short l = __builtin_bit_cast(unsigned short, __float2bfloat16(lo));
    unsigned short h = __builtin_bit_cast(unsigned short, __float2bfloat16(hi));
    return ((unsigned int)h << 16) | (unsigned int)l;
}

__device__ __forceinline__ bf16x8 frag_of(unsigned int a, unsigned int b,
                                          unsigned int c, unsigned int d) {
    u32x4 u; u[0] = a; u[1] = b; u[2] = c; u[3] = d;
    return __builtin_bit_cast(bf16x8, u);
}

__device__ __forceinline__ float bf16bits_lo(unsigned int w) {
    return __builtin_bit_cast(float, w << 16);
}
__device__ __forceinline__ float bf16bits_hi(unsigned int w) {
    return __builtin_bit_cast(float, w & 0xffff0000u);
}

// async global->LDS copy, 16B per lane (wave-uniform base + lane*16 dest)
__device__ __forceinline__ void gload_lds16(const uint4* g, uint4* l) {
    __builtin_amdgcn_global_load_lds(
        (const __attribute__((address_space(1))) unsigned int*)g,
        (__attribute__((address_space(3))) unsigned int*)l,
        16, 0, 0);
}

// Clamped weight fetch helpers (OOB -> 0)
__device__ __forceinline__ float ldW1f(const float* __restrict__ W1, int k, int j) {
    const bool ok = (k < TSTEPS) && (j < IN_DIM);
    const int  idx = ok ? ((GDIM + k) * IN_DIM + j) : 0;
    const float v = W1[idx];
    return ok ? v : 0.0f;
}
__device__ __forceinline__ float ldW2t(const float* __restrict__ W2, int j, int o) {
    const bool ok = (j < IN_DIM) && (o < HORIZON);
    const int  idx = ok ? (j * HORIZON + o) : 0;
    const float v = W2[idx];
    return ok ? v : 0.0f;
}

// ---------------------------------------------------------------------------
// Kernel 1 (grid 257 x 1024):
//  blocks 0..255 : patch_hb[p][j] = bf16(b1[j] + sum_{i<192} x[p][i]*W1[i][j])
//                  4-way i-split (48 i each, unroll 16 -> 3 latency batches),
//                  LDS combine of 3 partials.
//  block 256     : pack per-lane MFMA weight fragments (stacked k-layout
//                  m(e,hi) = (e&3)+8*(e>>2)+4*hi) into wfrag.
// ---------------------------------------------------------------------------
__global__ __launch_bounds__(1024) void precompute(
    const float* __restrict__ mixer_x,   // (1,12,256,16)
    const float* __restrict__ W1,        // (204,204)
    const float* __restrict__ b1,        // (204)
    const float* __restrict__ W2,        // (204,12)
    unsigned short* __restrict__ patch_hb, // (256,204) bf16
    u32x4* __restrict__ wfrag)           // (20,64)
{
    const int blk = blockIdx.x;
    const int tid = threadIdx.x;

    if (blk == N_PATCHES) {
        const int lane = tid & 63;
        const int g    = tid >> 6;        // 0..15
        const int jl   = lane & 31;
        const int kb   = 4 * (lane >> 5);
        for (int f = g; f < 20; f += 16) {
            u32x4 u;
            if (f < 7) {
                const int j = f * 32 + jl;
                u[0] = pk2(ldW1f(W1, kb + 0,  j), ldW1f(W1, kb + 1,  j));
                u[1] = pk2(ldW1f(W1, kb + 2,  j), ldW1f(W1, kb + 3,  j));
                u[2] = pk2(ldW1f(W1, kb + 8,  j), ldW1f(W1, kb + 9,  j));
                u[3] = pk2(ldW1f(W1, kb + 10, j), ldW1f(W1, kb + 11, j));
            } else {
                const int j0 = (f - 7) * 16 + kb;
                u[0] = pk2(ldW2t(W2, j0 + 0,  jl), ldW2t(W2, j0 + 1,  jl));
                u[1] = pk2(ldW2t(W2, j0 + 2,  jl), ldW2t(W2, j0 + 3,  jl));
                u[2] = pk2(ldW2t(W2, j0 + 8,  jl), ldW2t(W2, j0 + 9,  jl));
                u[3] = pk2(ldW2t(W2, j0 + 10, jl), ldW2t(W2, j0 + 11, jl));
            }
            wfrag[f * 64 + lane] = u;
        }
        return;
    }

    __shared__ float xs[GDIM];
    __shared__ float partial[3 * IN_DIM];
    const int p = blk;
    const int j = tid & 255;
    const int q = tid >> 8;               // i-quarter 0..3

    if (tid < GDIM) {
        const int t = tid >> 4, f = tid & 15;
        xs[tid] = mixer_x[(t * N_PATCHES + p) * NHID + f];
    }
    __syncthreads();

    float acc = 0.0f;
    if (j < IN_DIM) {
        acc = (q == 0) ? b1[j] : 0.0f;
        const int ibase = q * 48;
#pragma unroll 16
        for (int i = 0; i < 48; ++i)
            acc = fmaf(xs[ibase + i], W1[(ibase + i) * IN_DIM + j], acc);
        if (q > 0) partial[(q - 1) * IN_DIM + j] = acc;
    }
    __syncthreads();
    if (q == 0 && j < IN_DIM) {
        const float v = acc + partial[j] + partial[IN_DIM + j] + partial[2 * IN_DIM + j];
        patch_hb[p * IN_DIM + j] =
            __builtin_bit_cast(unsigned short, __float2bfloat16(v));
    }
}

// ---------------------------------------------------------------------------
// Kernel 2 (grid 256 x 512, 104448 B LDS, 2 waves/SIMD): stage full bf16
// patch table into LDS via async global_load_lds (13 x 16B/lane issues, one
// barrier drain), then per-wave MFMA over chunks of 32 consecutive nodes
// (flat index c = blk*8+wid, stride 2048). First chunk's feature/patch-idx
// loads issue BEFORE staging so their latency hides under it.
// GEMM1 (swapped): h^T = W1f^T x F^T + PH (C-init from LDS)
// GEMM2 (swapped): out^T = sum_kt W2^T x h-tile, split even/odd accumulators.
// ---------------------------------------------------------------------------
__global__ __launch_bounds__(512) void node_mlp_mfma(
    const float* __restrict__ features,       // (200000,12)
    const int*   __restrict__ node_patch,     // (200000)
    const unsigned short* __restrict__ patch_hb, // (256,204) bf16
    const u32x4* __restrict__ wfrag,          // (20,64)
    const float* __restrict__ b2,             // (12)
    float* __restrict__ out)                  // (200000,12)
{
    __shared__ unsigned short smem[N_PATCHES * IN_DIM];   // 104448 B

    const int tid  = threadIdx.x;
    const int lane = tid & 63;
    const int wid  = tid >> 6;
    const int jl   = lane & 31;
    const int hi   = lane >> 5;

    // ---- first chunk's loads: issue before staging ------------------------
    int c = blockIdx.x * 8 + wid;                         // 0..2047
    float4 fa, fb, fc; int p;
    {
        const float4* fp = (const float4*)(features + (c * 32 + jl) * TSTEPS);
        fa = fp[0]; fb = fp[1]; fc = fp[2];
        p  = node_patch[c * 32 + jl];
    }

    bf16x8 A1f[7], A2f[13];
#pragma unroll
    for (int f = 0; f < 7; ++f)
        A1f[f] = __builtin_bit_cast(bf16x8, wfrag[f * 64 + lane]);
#pragma unroll
    for (int f = 0; f < 13; ++f)
        A2f[f] = __builtin_bit_cast(bf16x8, wfrag[(7 + f) * 64 + lane]);

    const float4 b2A = *(const float4*)(b2 + 4 * hi);     // b2[0..3] / b2[4..7]
    const float4 b2B = *(const float4*)(b2 + 8);          // b2[8..11] (hi0)

    // ---- async stage bf16 patch table -> LDS ------------------------------
    {
        const uint4* src = (const uint4*)patch_hb;
        uint4* dst = (uint4*)smem;
#pragma unroll
        for (int k = 0; k < 13; ++k) {
            const int i = tid + k * K2_THREADS;
            if (i < TBL_U4) gload_lds16(src + i, dst + i);
        }
    }
    __syncthreads();   // drains vmcnt (incl. global_load_lds) + lgkm

    // ---- chunk loop with depth-1 software pipeline ------------------------
    while (true) {
        const int  cn    = c + TOTAL_WAVES;
        const bool haveN = (cn < NCHUNKS);
        float4 fa2, fb2, fc2; int p2 = 0;
        if (haveN) {                                      // prefetch next chunk
            const float4* fq = (const float4*)(features + (cn * 32 + jl) * TSTEPS);
            fa2 = fq[0]; fb2 = fq[1]; fc2 = fq[2];
            p2  = node_patch[cn * 32 + jl];
        }

        // B1: F^T[k][node], stacked layout (k>=12 -> 0)
        const bf16x8 B1 = frag_of(hi ? pk2(fb.x, fb.y) : pk2(fa.x, fa.y),
                                  hi ? pk2(fb.z, fb.w) : pk2(fa.z, fa.w),
                                  hi ? 0u              : pk2(fc.x, fc.y),
                                  hi ? 0u              : pk2(fc.z, fc.w));

        const unsigned short* row = smem + p * IN_DIM;

        f32x16 oE, oO;
#pragma unroll
        for (int e = 0; e < 16; ++e) { oE[e] = 0.0f; oO[e] = 0.0f; }

#pragma unroll
        for (int t = 0; t < 7; ++t) {
            f32x16 acc;
#pragma unroll
            for (int G = 0; G < 4; ++G) {
                const int eoff = t * 32 + 8 * G + 4 * hi;
                const bool ok  = (eoff <= 200);           // eoff+3 <= 203
                const uint2 r  = *(const uint2*)(row + (ok ? eoff : 0));
                acc[4 * G + 0] = ok ? bf16bits_lo(r.x) : 0.0f;
                acc[4 * G + 1] = ok ? bf16bits_hi(r.x) : 0.0f;
                acc[4 * G + 2] = ok ? bf16bits_lo(r.y) : 0.0f;
                acc[4 * G + 3] = ok ? bf16bits_hi(r.y) : 0.0f;
            }

            acc = __builtin_amdgcn_mfma_f32_32x32x16_bf16(A1f[t], B1, acc, 0, 0, 0);

            const bf16x8 ba = frag_of(
                pk2(fmaxf(acc[0], 0.f), fmaxf(acc[1], 0.f)),
                pk2(fmaxf(acc[2], 0.f), fmaxf(acc[3], 0.f)),
                pk2(fmaxf(acc[4], 0.f), fmaxf(acc[5], 0.f)),
                pk2(fmaxf(acc[6], 0.f), fmaxf(acc[7], 0.f)));
            oE = __builtin_amdgcn_mfma_f32_32x32x16_bf16(A2f[2 * t], ba, oE, 0, 0, 0);

            if (t < 6) {
                const bf16x8 bb = frag_of(
                    pk2(fmaxf(acc[8],  0.f), fmaxf(acc[9],  0.f)),
                    pk2(fmaxf(acc[10], 0.f), fmaxf(acc[11], 0.f)),
                    pk2(fmaxf(acc[12], 0.f), fmaxf(acc[13], 0.f)),
                    pk2(fmaxf(acc[14], 0.f), fmaxf(acc[15], 0.f)));
                oO = __builtin_amdgcn_mfma_f32_32x32x16_bf16(A2f[2 * t + 1], bb, oO, 0, 0, 0);
            }
        }

        // ---- store: D row of elem e = (e&3)+8*(e>>2)+4*hi, col = node -----
        {
            const int node = c * 32 + jl;                 // always < N_NODES
            float* orow = out + node * HORIZON;
            const float s0 = oE[0] + oO[0], s1 = oE[1] + oO[1];
            const float s2 = oE[2] + oO[2], s3 = oE[3] + oO[3];
            if (hi == 0) {
                const float s4 = oE[4] + oO[4], s5 = oE[5] + oO[5];
                const float s6 = oE[6] + oO[6], s7 = oE[7] + oO[7];
                *(float4*)(orow + 0) = make_float4(s0 + b2A.x, s1 + b2A.y,
                                                   s2 + b2A.z, s3 + b2A.w);
                *(float4*)(orow + 8) = make_float4(s4 + b2B.x, s5 + b2B.y,
                                                   s6 + b2B.z, s7 + b2B.w);
            } else {
                *(float4*)(orow + 4) = make_float4(s0 + b2A.x, s1 + b2A.y,
                                                   s2 + b2A.z, s3 + b2A.w);
            }
        }

        if (!haveN) break;
        fa = fa2; fb = fb2; fc = fc2; p = p2; c = cn;
    }
}

// ---------------------------------------------------------------------------
extern "C" void kernel_launch(void* const* d_in, const int* in_sizes, int n_in,
                              void* d_out, int out_size, void* d_ws, size_t ws_size,
                              hipStream_t stream) {
    const float* mixer_x    = (const float*)d_in[0];
    const float* features   = (const float*)d_in[1];
    const float* W1         = (const float*)d_in[2];
    const float* b1         = (const float*)d_in[3];
    const float* W2         = (const float*)d_in[4];
    const float* b2         = (const float*)d_in[5];
    const int*   node_patch = (const int*)d_in[6];
    float* out = (float*)d_out;

    unsigned short* patch_hb = (unsigned short*)d_ws;          // 104448 B
    u32x4*          wfrag    = (u32x4*)((char*)d_ws + 104448); // +20480 B

    precompute<<<257, 1024, 0, stream>>>(mixer_x, W1, b1, W2, patch_hb, wfrag);

    node_mlp_mfma<<<256, K2_THREADS, 0, stream>>>(features, node_patch,
                                                  patch_hb, wfrag, b2, out);
}